// Round 2
// baseline (265.334 us; speedup 1.0000x reference)
//
#include <hip/hip_runtime.h>

// Problem constants: B=32, L=1024, D_MODEL=128, D_INNER=256, D_STATE=16, D_CONV=4, DT_RANK=8
// Workspace layout (float offsets):
#define WS_P    0        // p[512]   = W_in @ W_emb[:,0]
#define WS_Q    512      // q[512]   = W_in @ b_emb
#define WS_V    1024     // v[256]   = W_out^T @ W_fc^T
#define WS_ANEG 1280     // aneg[256*16] = -exp(A_log)
#define WS_WXT  5376     // WxT[256*40]  = W_x transposed
#define WS_S1   15616    // slot1[1024]  per-k1-block partial of sum(u*D*silu(z)*v)
#define WS_S2   16640    // slot2[512]   per-k3-block partial of scan contribution
#define WS_DT   17408    // dt  [32768*256]
#define STRIDE_BD 8388608
// dtu = WS_DT + STRIDE_BD, sv = +2*STRIDE_BD, bc = +3*STRIDE_BD (32768*32)
// total ~26.2M floats ~= 105 MB

__global__ void k0_precompute(const float* __restrict__ W_emb,
                              const float* __restrict__ b_emb,
                              const float* __restrict__ W_in,
                              const float* __restrict__ W_x,
                              const float* __restrict__ A_log,
                              const float* __restrict__ W_out,
                              const float* __restrict__ W_fc,
                              float* __restrict__ ws) {
    int idx = blockIdx.x * 256 + threadIdx.x;
    if (idx < 512) {
        float sp = 0.f, sq = 0.f;
        const float* row = W_in + idx * 128;
        for (int d = 0; d < 128; ++d) {
            float w = row[d];
            sp = fmaf(w, W_emb[d], sp);
            sq = fmaf(w, b_emb[d], sq);
        }
        ws[WS_P + idx] = sp;
        ws[WS_Q + idx] = sq;
    } else if (idx < 768) {
        int d = idx - 512;
        float s = 0.f;
        for (int e = 0; e < 128; ++e) s = fmaf(W_fc[e], W_out[e * 256 + d], s);
        ws[WS_V + d] = s;
    } else if (idx < 4864) {
        int i = idx - 768;
        ws[WS_ANEG + i] = -__expf(A_log[i]);
    } else if (idx < 15104) {
        int i = idx - 4864;
        int d = i / 40, j = i - d * 40;
        ws[WS_WXT + i] = W_x[j * 256 + d];
    }
}

// Fused front-end: per block = 32 consecutive positions of one batch row.
// thread t = channel d for elementwise stages; wave-structured for x_db GEMV.
__global__ __launch_bounds__(256, 4) void k1_front(
        const float* __restrict__ x,
        const float* __restrict__ conv_w,
        const float* __restrict__ conv_b,
        const float* __restrict__ W_dt,
        const float* __restrict__ b_dt,
        const float* __restrict__ Dvec,
        float* __restrict__ ws) {
    __shared__ float u_s[32 * 257];   // [pos][d], pad 257 -> 2-way banks max
    __shared__ float xdb_s[32 * 41];  // [pos][j], pad 41
    __shared__ float x_s[36];
    __shared__ float red_s[256];

    const float* p = ws + WS_P;
    const float* q = ws + WS_Q;
    const float* v = ws + WS_V;
    const float* wxt = ws + WS_WXT;
    float* dt_g  = ws + WS_DT;
    float* dtu_g = dt_g + STRIDE_BD;
    float* sv_g  = dt_g + 2 * STRIDE_BD;
    float* bc_g  = dt_g + 3 * STRIDE_BD;

    int t = threadIdx.x;
    int b = blockIdx.x >> 5;
    int l0 = (blockIdx.x & 31) << 5;
    long posbase = b * 1024 + l0;

    if (t < 35) {
        int gi = l0 - 3 + t;
        x_s[t] = (gi >= 0) ? x[b * 1024 + gi] : 0.f;
    }

    // per-channel params (t = d)
    float pd = p[t], qd = q[t], pz = p[256 + t], qz = q[256 + t];
    float cw0 = conv_w[t], cw1 = conv_w[256 + t], cw2 = conv_w[512 + t], cw3 = conv_w[768 + t];
    float cb = conv_b[t], Dd = Dvec[t], vd = v[t];
    float wdt[8];
    #pragma unroll
    for (int r = 0; r < 8; ++r) wdt[r] = W_dt[t * 8 + r];
    float bdt = b_dt[t];
    __syncthreads();

    // Stage 1: conv -> u = silu(xc); z-gate -> sv = silu(z)*v[d]; accumulate u*D*sv
    float uDsv = 0.f;
    for (int pp = 0; pp < 32; ++pp) {
        int l = l0 + pp;
        float x0 = x_s[pp + 3];
        float s = cb + cw3 * fmaf(x0, pd, qd);
        if (l >= 3) {
            s += cw0 * fmaf(x_s[pp], pd, qd)
               + cw1 * fmaf(x_s[pp + 1], pd, qd)
               + cw2 * fmaf(x_s[pp + 2], pd, qd);
        } else {
            if (l >= 1) s += cw2 * fmaf(x_s[pp + 2], pd, qd);
            if (l >= 2) s += cw1 * fmaf(x_s[pp + 1], pd, qd);
        }
        float u = __fdividef(s, 1.f + __expf(-s));
        float z = fmaf(x0, pz, qz);
        float svv = __fdividef(z, 1.f + __expf(-z)) * vd;
        u_s[pp * 257 + t] = u;
        sv_g[(size_t)(posbase + pp) * 256 + t] = svv;
        uDsv = fmaf(u * Dd, svv, uDsv);
    }
    __syncthreads();

    // Stage 2: x_db[pos][0..39] = sum_d u[pos][d] * W_x[j][d]
    {
        int w = t >> 6;
        int lane = t & 63;
        int pos = lane & 31;
        int half = lane >> 5;
        float acc[10];
        #pragma unroll
        for (int jj = 0; jj < 10; ++jj) acc[jj] = 0.f;
        const float* urow  = u_s + pos * 257 + half * 128;
        const float* wbase = wxt + w * 10 + half * 128 * 40;
        for (int dd = 0; dd < 128; ++dd) {
            float uv = urow[dd];
            const float* wr = wbase + dd * 40;
            #pragma unroll
            for (int jj = 0; jj < 10; ++jj) acc[jj] = fmaf(uv, wr[jj], acc[jj]);
        }
        #pragma unroll
        for (int jj = 0; jj < 10; ++jj) acc[jj] += __shfl_down(acc[jj], 32);
        if (half == 0) {
            #pragma unroll
            for (int jj = 0; jj < 10; ++jj) xdb_s[pos * 41 + w * 10 + jj] = acc[jj];
        }
    }
    __syncthreads();

    // Stage 3: dt = softplus(x_db[0:8] @ W_dt^T + b_dt); store dt, dtu coalesced
    for (int pp = 0; pp < 32; ++pp) {
        const float* xr = xdb_s + pp * 41;
        float s = bdt;
        #pragma unroll
        for (int r = 0; r < 8; ++r) s = fmaf(xr[r], wdt[r], s);
        float dtv = fmaxf(s, 0.f) + log1pf(__expf(-fabsf(s)));
        float uv = u_s[pp * 257 + t];
        size_t off = (size_t)(posbase + pp) * 256 + t;
        dt_g[off] = dtv;
        dtu_g[off] = dtv * uv;
    }

    // Stage 4: write Bs|Cs (x_db[8:40]) as [pos][32]
    {
        int pp = t >> 3;
        int j0 = (t & 7) * 4;
        size_t off = (size_t)(posbase + pp) * 32 + j0;
        #pragma unroll
        for (int j = 0; j < 4; ++j) bc_g[off + j] = xdb_s[pp * 41 + 8 + j0 + j];
    }

    // Stage 5: deterministic block partial for the u*D*sv term
    red_s[t] = uDsv;
    __syncthreads();
    for (int st = 128; st > 0; st >>= 1) {
        if (t < st) red_s[t] += red_s[t + st];
        __syncthreads();
    }
    if (t == 0) ws[WS_S1 + blockIdx.x] = red_s[0];
}

// Scan: one thread per (b, d, n) recurrence; 16 n-lanes share dt/dtu/sv loads.
__global__ __launch_bounds__(256, 2) void k3_scan(float* __restrict__ ws) {
    __shared__ float red_s[256];
    const float* dt_g  = ws + WS_DT;
    const float* dtu_g = dt_g + STRIDE_BD;
    const float* sv_g  = dt_g + 2 * STRIDE_BD;
    const float* bc_g  = dt_g + 3 * STRIDE_BD;

    int t = threadIdx.x;
    int i = blockIdx.x * 256 + t;
    int b = i >> 12;
    int r = i & 4095;
    int d = r >> 4;
    int n = r & 15;

    float a = ws[WS_ANEG + r];
    const float* dtp  = dt_g  + (size_t)b * 262144 + d;
    const float* dtup = dtu_g + (size_t)b * 262144 + d;
    const float* svp  = sv_g  + (size_t)b * 262144 + d;
    const float* bcp  = bc_g  + (size_t)b * 32768 + n;

    float h = 0.f, acc = 0.f;
    #pragma unroll 4
    for (int l = 0; l < 1024; ++l) {
        float dtv  = dtp[l * 256];
        float dA   = __expf(dtv * a);
        float dtuv = dtup[l * 256];
        float Bv   = bcp[l * 32];
        float Cv   = bcp[l * 32 + 16];
        float svv  = svp[l * 256];
        h   = fmaf(dA, h, dtuv * Bv);
        acc = fmaf(h * Cv, svv, acc);
    }
    red_s[t] = acc;
    __syncthreads();
    for (int st = 128; st > 0; st >>= 1) {
        if (t < st) red_s[t] += red_s[t + st];
        __syncthreads();
    }
    if (t == 0) ws[WS_S2 + blockIdx.x] = red_s[0];
}

__global__ void k4_final(const float* __restrict__ b_fc, const float* __restrict__ ws,
                         float* __restrict__ out) {
    int b = threadIdx.x;
    if (b < 32) {
        float s = 0.f;
        for (int k = 0; k < 32; ++k) s += ws[WS_S1 + b * 32 + k];
        for (int k = 0; k < 16; ++k) s += ws[WS_S2 + b * 16 + k];
        float logit = s * (1.f / 1024.f) + b_fc[0];
        out[b] = __fdividef(1.f, 1.f + __expf(-logit));
    }
}

extern "C" void kernel_launch(void* const* d_in, const int* in_sizes, int n_in,
                              void* d_out, int out_size, void* d_ws, size_t ws_size,
                              hipStream_t stream) {
    const float* x      = (const float*)d_in[0];
    const float* W_emb  = (const float*)d_in[1];
    const float* b_emb  = (const float*)d_in[2];
    const float* W_in   = (const float*)d_in[3];
    const float* conv_w = (const float*)d_in[4];
    const float* conv_b = (const float*)d_in[5];
    const float* W_x    = (const float*)d_in[6];
    const float* W_dt   = (const float*)d_in[7];
    const float* b_dt   = (const float*)d_in[8];
    const float* A_log  = (const float*)d_in[9];
    const float* Dvec   = (const float*)d_in[10];
    const float* W_out  = (const float*)d_in[11];
    const float* W_fc   = (const float*)d_in[12];
    const float* b_fc   = (const float*)d_in[13];
    float* ws = (float*)d_ws;

    k0_precompute<<<59, 256, 0, stream>>>(W_emb, b_emb, W_in, W_x, A_log, W_out, W_fc, ws);
    k1_front<<<1024, 256, 0, stream>>>(x, conv_w, conv_b, W_dt, b_dt, Dvec, ws);
    k3_scan<<<512, 256, 0, stream>>>(ws);
    k4_final<<<1, 64, 0, stream>>>(b_fc, ws, (float*)d_out);
}

// Round 3
// 252.843 us; speedup vs baseline: 1.0494x; 1.0494x over previous
//
#include <hip/hip_runtime.h>

// Problem constants: B=32, L=1024, D_MODEL=128, D_INNER=256, D_STATE=16, D_CONV=4, DT_RANK=8
// Workspace layout (float offsets):
#define WS_P    0        // p[512]   = W_in @ W_emb[:,0]
#define WS_Q    512      // q[512]   = W_in @ b_emb
#define WS_V    1024     // v[256]   = W_out^T @ W_fc^T
#define WS_ANEG 1280     // aneg[256*16] = -exp(A_log)
#define WS_WXT  5376     // WxT[256][48] padded: group g cols g*12..g*12+9 hold j=g*10..g*10+9
#define WS_S1   17664    // slot1[1024]  per-k1-block partial of sum(u*D*silu(z)*v)
#define WS_S2   18688    // slot2[512]   per-k3-block partial of scan contribution
#define WS_DT   19200    // dt  [32768*256]
#define STRIDE_BD 8388608
// dtu = WS_DT + STRIDE_BD, sv = +2*STRIDE_BD, bc = +3*STRIDE_BD (32768*32)
// total ~26.23M floats ~= 105 MB

__global__ void k0_precompute(const float* __restrict__ W_emb,
                              const float* __restrict__ b_emb,
                              const float* __restrict__ W_in,
                              const float* __restrict__ W_x,
                              const float* __restrict__ A_log,
                              const float* __restrict__ W_out,
                              const float* __restrict__ W_fc,
                              float* __restrict__ ws) {
    int idx = blockIdx.x * 256 + threadIdx.x;
    if (idx < 512) {
        float sp = 0.f, sq = 0.f;
        const float* row = W_in + idx * 128;
        for (int d = 0; d < 128; ++d) {
            float w = row[d];
            sp = fmaf(w, W_emb[d], sp);
            sq = fmaf(w, b_emb[d], sq);
        }
        ws[WS_P + idx] = sp;
        ws[WS_Q + idx] = sq;
    } else if (idx < 768) {
        int d = idx - 512;
        float s = 0.f;
        for (int e = 0; e < 128; ++e) s = fmaf(W_fc[e], W_out[e * 256 + d], s);
        ws[WS_V + d] = s;
    } else if (idx < 4864) {
        int i = idx - 768;
        ws[WS_ANEG + i] = -__expf(A_log[i]);
    } else if (idx < 17152) {
        int i = idx - 4864;            // [0, 256*48)
        int d = i / 48, c = i - d * 48;
        int g = c / 12, cj = c - g * 12;
        ws[WS_WXT + i] = (cj < 10) ? W_x[(g * 10 + cj) * 256 + d] : 0.f;
    }
}

// Fused front-end: per block = 32 consecutive positions of one batch row.
// thread t = channel d for elementwise stages; wave-structured for x_db GEMV.
__global__ __launch_bounds__(256, 4) void k1_front(
        const float* __restrict__ x,
        const float* __restrict__ conv_w,
        const float* __restrict__ conv_b,
        const float* __restrict__ W_dt,
        const float* __restrict__ b_dt,
        const float* __restrict__ Dvec,
        float* __restrict__ ws) {
    __shared__ float u_s[32 * 257];   // [pos][d], pad 257 -> 2-way banks max
    __shared__ float xdb_s[32 * 41];  // [pos][j], pad 41
    __shared__ float x_s[36];
    __shared__ float red_s[256];

    const float* p = ws + WS_P;
    const float* q = ws + WS_Q;
    const float* v = ws + WS_V;
    const float* wxt = ws + WS_WXT;
    float* dt_g  = ws + WS_DT;
    float* dtu_g = dt_g + STRIDE_BD;
    float* sv_g  = dt_g + 2 * STRIDE_BD;
    float* bc_g  = dt_g + 3 * STRIDE_BD;

    int t = threadIdx.x;
    int b = blockIdx.x >> 5;
    int l0 = (blockIdx.x & 31) << 5;
    long posbase = b * 1024 + l0;

    if (t < 35) {
        int gi = l0 - 3 + t;
        x_s[t] = (gi >= 0) ? x[b * 1024 + gi] : 0.f;
    }

    // per-channel params (t = d)
    float pd = p[t], qd = q[t], pz = p[256 + t], qz = q[256 + t];
    float cw0 = conv_w[t], cw1 = conv_w[256 + t], cw2 = conv_w[512 + t], cw3 = conv_w[768 + t];
    float cb = conv_b[t], Dd = Dvec[t], vd = v[t];
    float wdt[8];
    #pragma unroll
    for (int r = 0; r < 8; ++r) wdt[r] = W_dt[t * 8 + r];
    float bdt = b_dt[t];
    __syncthreads();

    // Stage 1: conv -> u = silu(xc); z-gate -> sv = silu(z)*v[d]; accumulate u*D*sv
    float uDsv = 0.f;
    for (int pp = 0; pp < 32; ++pp) {
        int l = l0 + pp;
        float x0 = x_s[pp + 3];
        float s = cb + cw3 * fmaf(x0, pd, qd);
        if (l >= 3) {
            s += cw0 * fmaf(x_s[pp], pd, qd)
               + cw1 * fmaf(x_s[pp + 1], pd, qd)
               + cw2 * fmaf(x_s[pp + 2], pd, qd);
        } else {
            if (l >= 1) s += cw2 * fmaf(x_s[pp + 2], pd, qd);
            if (l >= 2) s += cw1 * fmaf(x_s[pp + 1], pd, qd);
        }
        float u = __fdividef(s, 1.f + __expf(-s));
        float z = fmaf(x0, pz, qz);
        float svv = __fdividef(z, 1.f + __expf(-z)) * vd;
        u_s[pp * 257 + t] = u;
        sv_g[(size_t)(posbase + pp) * 256 + t] = svv;
        uDsv = fmaf(u * Dd, svv, uDsv);
    }
    __syncthreads();

    // Stage 2: x_db[pos][0..39] = sum_d u[pos][d] * W_x[j][d]
    // wave w owns j in [w*10, w*10+10); lane = (half, pos); halves split d-range.
    // WxT padded rows of 48 -> 16B-aligned float4 loads for the 10-wide j group.
    {
        int w = t >> 6;
        int lane = t & 63;
        int pos = lane & 31;
        int half = lane >> 5;
        float acc[10];
        #pragma unroll
        for (int jj = 0; jj < 10; ++jj) acc[jj] = 0.f;
        const float* urow  = u_s + pos * 257 + half * 128;
        const float* wbase = wxt + w * 12 + half * 128 * 48;
        #pragma unroll 4
        for (int dd = 0; dd < 128; ++dd) {
            float uv = urow[dd];
            const float* wr = wbase + dd * 48;
            float4 w0 = *(const float4*)wr;
            float4 w1 = *(const float4*)(wr + 4);
            float2 w2 = *(const float2*)(wr + 8);
            acc[0] = fmaf(uv, w0.x, acc[0]);
            acc[1] = fmaf(uv, w0.y, acc[1]);
            acc[2] = fmaf(uv, w0.z, acc[2]);
            acc[3] = fmaf(uv, w0.w, acc[3]);
            acc[4] = fmaf(uv, w1.x, acc[4]);
            acc[5] = fmaf(uv, w1.y, acc[5]);
            acc[6] = fmaf(uv, w1.z, acc[6]);
            acc[7] = fmaf(uv, w1.w, acc[7]);
            acc[8] = fmaf(uv, w2.x, acc[8]);
            acc[9] = fmaf(uv, w2.y, acc[9]);
        }
        #pragma unroll
        for (int jj = 0; jj < 10; ++jj) acc[jj] += __shfl_down(acc[jj], 32);
        if (half == 0) {
            #pragma unroll
            for (int jj = 0; jj < 10; ++jj) xdb_s[pos * 41 + w * 10 + jj] = acc[jj];
        }
    }
    __syncthreads();

    // Stage 3: dt = softplus(x_db[0:8] @ W_dt^T + b_dt); store dt, dtu coalesced
    for (int pp = 0; pp < 32; ++pp) {
        const float* xr = xdb_s + pp * 41;
        float s = bdt;
        #pragma unroll
        for (int r = 0; r < 8; ++r) s = fmaf(xr[r], wdt[r], s);
        float dtv = fmaxf(s, 0.f) + log1pf(__expf(-fabsf(s)));
        float uv = u_s[pp * 257 + t];
        size_t off = (size_t)(posbase + pp) * 256 + t;
        dt_g[off] = dtv;
        dtu_g[off] = dtv * uv;
    }

    // Stage 4: write Bs|Cs (x_db[8:40]) as [pos][32]
    {
        int pp = t >> 3;
        int j0 = (t & 7) * 4;
        size_t off = (size_t)(posbase + pp) * 32 + j0;
        #pragma unroll
        for (int j = 0; j < 4; ++j) bc_g[off + j] = xdb_s[pp * 41 + 8 + j0 + j];
    }

    // Stage 5: deterministic block partial for the u*D*sv term
    red_s[t] = uDsv;
    __syncthreads();
    for (int st = 128; st > 0; st >>= 1) {
        if (t < st) red_s[t] += red_s[t + st];
        __syncthreads();
    }
    if (t == 0) ws[WS_S1 + blockIdx.x] = red_s[0];
}

// Scan with L-chunk decomposition: block = 1024 threads = 256 recurrences x 4 chunks.
// Per chunk: T = prod(dA), g_end = local h (h_in=0), accL = sum(w*g), WE = sum(w*E).
// Exact recombine in LDS: acc += accL + h*WE; h = T*h + g_end.
__global__ __launch_bounds__(1024, 2) void k3_scan(float* __restrict__ ws) {
    __shared__ float T_s[1024], G_s[1024], AL_s[1024], WE_s[1024];
    __shared__ float red_s[256];
    const float* dt_g  = ws + WS_DT;
    const float* dtu_g = dt_g + STRIDE_BD;
    const float* sv_g  = dt_g + 2 * STRIDE_BD;
    const float* bc_g  = dt_g + 3 * STRIDE_BD;

    int t = threadIdx.x;
    int rec = t & 255;
    int c = t >> 8;                 // chunk 0..3
    int b = blockIdx.x >> 4;
    int dblk = blockIdx.x & 15;
    int d = dblk * 16 + (rec >> 4);
    int n = rec & 15;
    int r = d * 16 + n;

    float a = ws[WS_ANEG + r];
    int l0 = c << 8;                // chunk base in L
    const float* dtp  = dt_g  + (size_t)b * 262144 + (size_t)l0 * 256 + d;
    const float* dtup = dtu_g + (size_t)b * 262144 + (size_t)l0 * 256 + d;
    const float* svp  = sv_g  + (size_t)b * 262144 + (size_t)l0 * 256 + d;
    const float* bcp  = bc_g  + (size_t)b * 32768 + (size_t)l0 * 32 + n;

    float E = 1.f, g = 0.f, accL = 0.f, WEa = 0.f;
    #pragma unroll 2
    for (int l = 0; l < 256; ++l) {
        float dtv  = dtp[l * 256];
        float dA   = __expf(dtv * a);
        float dtuv = dtup[l * 256];
        float Bv   = bcp[l * 32];
        float Cv   = bcp[l * 32 + 16];
        float svv  = svp[l * 256];
        g = fmaf(dA, g, dtuv * Bv);
        E *= dA;
        float wgt = Cv * svv;
        accL = fmaf(g, wgt, accL);
        WEa  = fmaf(E, wgt, WEa);
    }
    T_s[t] = E; G_s[t] = g; AL_s[t] = accL; WE_s[t] = WEa;
    __syncthreads();

    if (t < 256) {
        float acc = AL_s[t];        // chunk 0 (h_in = 0)
        float h   = G_s[t];
        #pragma unroll
        for (int cc = 1; cc < 4; ++cc) {
            acc += AL_s[cc * 256 + t] + h * WE_s[cc * 256 + t];
            h = fmaf(T_s[cc * 256 + t], h, G_s[cc * 256 + t]);
        }
        red_s[t] = acc;
    }
    __syncthreads();
    for (int st = 128; st > 0; st >>= 1) {
        if (t < st) red_s[t] += red_s[t + st];
        __syncthreads();
    }
    if (t == 0) ws[WS_S2 + blockIdx.x] = red_s[0];
}

__global__ void k4_final(const float* __restrict__ b_fc, const float* __restrict__ ws,
                         float* __restrict__ out) {
    int b = threadIdx.x;
    if (b < 32) {
        float s = 0.f;
        for (int k = 0; k < 32; ++k) s += ws[WS_S1 + b * 32 + k];
        for (int k = 0; k < 16; ++k) s += ws[WS_S2 + b * 16 + k];
        float logit = s * (1.f / 1024.f) + b_fc[0];
        out[b] = __fdividef(1.f, 1.f + __expf(-logit));
    }
}

extern "C" void kernel_launch(void* const* d_in, const int* in_sizes, int n_in,
                              void* d_out, int out_size, void* d_ws, size_t ws_size,
                              hipStream_t stream) {
    const float* x      = (const float*)d_in[0];
    const float* W_emb  = (const float*)d_in[1];
    const float* b_emb  = (const float*)d_in[2];
    const float* W_in   = (const float*)d_in[3];
    const float* conv_w = (const float*)d_in[4];
    const float* conv_b = (const float*)d_in[5];
    const float* W_x    = (const float*)d_in[6];
    const float* W_dt   = (const float*)d_in[7];
    const float* b_dt   = (const float*)d_in[8];
    const float* A_log  = (const float*)d_in[9];
    const float* Dvec   = (const float*)d_in[10];
    const float* W_out  = (const float*)d_in[11];
    const float* W_fc   = (const float*)d_in[12];
    const float* b_fc   = (const float*)d_in[13];
    float* ws = (float*)d_ws;

    k0_precompute<<<67, 256, 0, stream>>>(W_emb, b_emb, W_in, W_x, A_log, W_out, W_fc, ws);
    k1_front<<<1024, 256, 0, stream>>>(x, conv_w, conv_b, W_dt, b_dt, Dvec, ws);
    k3_scan<<<512, 1024, 0, stream>>>(ws);
    k4_final<<<1, 64, 0, stream>>>(b_fc, ws, (float*)d_out);
}

// Round 4
// 214.270 us; speedup vs baseline: 1.2383x; 1.1800x over previous
//
#include <hip/hip_runtime.h>

// Problem constants: B=32, L=1024, D_MODEL=128, D_INNER=256, D_STATE=16, D_CONV=4, DT_RANK=8
// Workspace layout (float offsets):
#define WS_P    0        // p[512]   = W_in @ W_emb[:,0]
#define WS_Q    512      // q[512]   = W_in @ b_emb
#define WS_V    1024     // v[256]   = W_out^T @ W_fc^T
#define WS_ANEG 1280     // aneg[256*16] = -exp(A_log)
#define WS_WXT  5376     // WxT[256][48] padded: group g cols g*12..g*12+9 hold j=g*10..g*10+9
#define WS_S1   17664    // slot1[1024]  per-k1-block partial of sum(u*D*silu(z)*v)
#define WS_S2   18688    // slot2[512]   per-k3-block partial of scan contribution
#define WS_DT   19200    // dt  [32768*256]
#define STRIDE_BD 8388608
// dtu = WS_DT + STRIDE_BD, sv = +2*STRIDE_BD, bc = +3*STRIDE_BD (32768*32)

__global__ void k0_precompute(const float* __restrict__ W_emb,
                              const float* __restrict__ b_emb,
                              const float* __restrict__ W_in,
                              const float* __restrict__ W_x,
                              const float* __restrict__ A_log,
                              const float* __restrict__ W_out,
                              const float* __restrict__ W_fc,
                              float* __restrict__ ws) {
    int idx = blockIdx.x * 256 + threadIdx.x;
    if (idx < 512) {
        float sp = 0.f, sq = 0.f;
        const float* row = W_in + idx * 128;
        for (int d = 0; d < 128; ++d) {
            float w = row[d];
            sp = fmaf(w, W_emb[d], sp);
            sq = fmaf(w, b_emb[d], sq);
        }
        ws[WS_P + idx] = sp;
        ws[WS_Q + idx] = sq;
    } else if (idx < 768) {
        int d = idx - 512;
        float s = 0.f;
        for (int e = 0; e < 128; ++e) s = fmaf(W_fc[e], W_out[e * 256 + d], s);
        ws[WS_V + d] = s;
    } else if (idx < 4864) {
        int i = idx - 768;
        ws[WS_ANEG + i] = -__expf(A_log[i]);
    } else if (idx < 17152) {
        int i = idx - 4864;            // [0, 256*48)
        int d = i / 48, c = i - d * 48;
        int g = c / 12, cj = c - g * 12;
        ws[WS_WXT + i] = (cj < 10) ? W_x[(g * 10 + cj) * 256 + d] : 0.f;
    }
}

// Fused front-end: per block = 32 consecutive positions of one batch row.
__global__ __launch_bounds__(256, 4) void k1_front(
        const float* __restrict__ x,
        const float* __restrict__ conv_w,
        const float* __restrict__ conv_b,
        const float* __restrict__ W_dt,
        const float* __restrict__ b_dt,
        const float* __restrict__ Dvec,
        float* __restrict__ ws) {
    __shared__ float u_s[32 * 257];   // [pos][d]
    __shared__ float xdb_s[32 * 41];  // [pos][j]
    __shared__ float x_s[36];
    __shared__ float red_s[256];

    const float* p = ws + WS_P;
    const float* q = ws + WS_Q;
    const float* v = ws + WS_V;
    const float* wxt = ws + WS_WXT;
    float* dt_g  = ws + WS_DT;
    float* dtu_g = dt_g + STRIDE_BD;
    float* sv_g  = dt_g + 2 * STRIDE_BD;
    float* bc_g  = dt_g + 3 * STRIDE_BD;

    int t = threadIdx.x;
    int b = blockIdx.x >> 5;
    int l0 = (blockIdx.x & 31) << 5;
    long posbase = b * 1024 + l0;

    if (t < 35) {
        int gi = l0 - 3 + t;
        x_s[t] = (gi >= 0) ? x[b * 1024 + gi] : 0.f;
    }

    // per-channel params (t = d)
    float pd = p[t], qd = q[t], pz = p[256 + t], qz = q[256 + t];
    float cw0 = conv_w[t], cw1 = conv_w[256 + t], cw2 = conv_w[512 + t], cw3 = conv_w[768 + t];
    float cb = conv_b[t], Dd = Dvec[t], vd = v[t];
    float wdt[8];
    #pragma unroll
    for (int r = 0; r < 8; ++r) wdt[r] = W_dt[t * 8 + r];
    float bdt = b_dt[t];
    __syncthreads();

    // Stage 1: conv -> u = silu(xc); z-gate -> sv = silu(z)*v[d]; accumulate u*D*sv
    float uDsv = 0.f;
    for (int pp = 0; pp < 32; ++pp) {
        int l = l0 + pp;
        float x0 = x_s[pp + 3];
        float s = cb + cw3 * fmaf(x0, pd, qd);
        if (l >= 3) {
            s += cw0 * fmaf(x_s[pp], pd, qd)
               + cw1 * fmaf(x_s[pp + 1], pd, qd)
               + cw2 * fmaf(x_s[pp + 2], pd, qd);
        } else {
            if (l >= 1) s += cw2 * fmaf(x_s[pp + 2], pd, qd);
            if (l >= 2) s += cw1 * fmaf(x_s[pp + 1], pd, qd);
        }
        float u = __fdividef(s, 1.f + __expf(-s));
        float z = fmaf(x0, pz, qz);
        float svv = __fdividef(z, 1.f + __expf(-z)) * vd;
        u_s[pp * 257 + t] = u;
        sv_g[(size_t)(posbase + pp) * 256 + t] = svv;
        uDsv = fmaf(u * Dd, svv, uDsv);
    }
    __syncthreads();

    // Stage 2: x_db[pos][0..39] = sum_d u[pos][d] * W_x[j][d]
    // wave w owns 10 j; lane = (pg: 4-pos group, ds: d-slice of 8);
    // each W element loaded once serves 4 pos-FMAs (register blocking).
    {
        int w = t >> 6;
        int lane = t & 63;
        int pg = lane >> 3;          // 8 pos-groups x 4 pos = 32 pos
        int ds = lane & 7;           // 8 d-slices; dd = ds + 8*i
        float acc[4][10];
        #pragma unroll
        for (int pp = 0; pp < 4; ++pp)
            #pragma unroll
            for (int jj = 0; jj < 10; ++jj) acc[pp][jj] = 0.f;
        const float* wbase = wxt + w * 12;
        const float* ub = u_s + (pg * 4) * 257;
        for (int i = 0; i < 32; ++i) {
            int dd = ds + 8 * i;
            const float* wr = wbase + dd * 48;
            float4 w0 = *(const float4*)wr;
            float4 w1 = *(const float4*)(wr + 4);
            float2 w2 = *(const float2*)(wr + 8);
            float u0 = ub[dd];
            float u1 = ub[257 + dd];
            float u2 = ub[2 * 257 + dd];
            float u3 = ub[3 * 257 + dd];
            #define K1_FMAS(pp, uv) \
                acc[pp][0] = fmaf(uv, w0.x, acc[pp][0]); \
                acc[pp][1] = fmaf(uv, w0.y, acc[pp][1]); \
                acc[pp][2] = fmaf(uv, w0.z, acc[pp][2]); \
                acc[pp][3] = fmaf(uv, w0.w, acc[pp][3]); \
                acc[pp][4] = fmaf(uv, w1.x, acc[pp][4]); \
                acc[pp][5] = fmaf(uv, w1.y, acc[pp][5]); \
                acc[pp][6] = fmaf(uv, w1.z, acc[pp][6]); \
                acc[pp][7] = fmaf(uv, w1.w, acc[pp][7]); \
                acc[pp][8] = fmaf(uv, w2.x, acc[pp][8]); \
                acc[pp][9] = fmaf(uv, w2.y, acc[pp][9]);
            K1_FMAS(0, u0)
            K1_FMAS(1, u1)
            K1_FMAS(2, u2)
            K1_FMAS(3, u3)
            #undef K1_FMAS
        }
        // reduce over the 8 d-slices (lane-stride 1 within each pos-group)
        #pragma unroll
        for (int m = 1; m <= 4; m <<= 1)
            #pragma unroll
            for (int pp = 0; pp < 4; ++pp)
                #pragma unroll
                for (int jj = 0; jj < 10; ++jj)
                    acc[pp][jj] += __shfl_xor(acc[pp][jj], m);
        if (ds == 0) {
            #pragma unroll
            for (int pp = 0; pp < 4; ++pp)
                #pragma unroll
                for (int jj = 0; jj < 10; ++jj)
                    xdb_s[(pg * 4 + pp) * 41 + w * 10 + jj] = acc[pp][jj];
        }
    }
    __syncthreads();

    // Stage 3: dt = softplus(x_db[0:8] @ W_dt^T + b_dt); store dt, dtu coalesced
    for (int pp = 0; pp < 32; ++pp) {
        const float* xr = xdb_s + pp * 41;
        float s = bdt;
        #pragma unroll
        for (int r = 0; r < 8; ++r) s = fmaf(xr[r], wdt[r], s);
        float dtv = fmaxf(s, 0.f) + log1pf(__expf(-fabsf(s)));
        float uv = u_s[pp * 257 + t];
        size_t off = (size_t)(posbase + pp) * 256 + t;
        dt_g[off] = dtv;
        dtu_g[off] = dtv * uv;
    }

    // Stage 4: write Bs|Cs (x_db[8:40]) as [pos][32]
    {
        int pp = t >> 3;
        int j0 = (t & 7) * 4;
        size_t off = (size_t)(posbase + pp) * 32 + j0;
        #pragma unroll
        for (int j = 0; j < 4; ++j) bc_g[off + j] = xdb_s[pp * 41 + 8 + j0 + j];
    }

    // Stage 5: deterministic block partial for the u*D*sv term
    red_s[t] = uDsv;
    __syncthreads();
    for (int st = 128; st > 0; st >>= 1) {
        if (t < st) red_s[t] += red_s[t + st];
        __syncthreads();
    }
    if (t == 0) ws[WS_S1 + blockIdx.x] = red_s[0];
}

// Scan: block = (b, dgroup of 64 d, ngroup of 4 n). 1024 threads = 16 L-chunks x
// (16 d-quads x 4 n). Each thread advances 4 recurrences (d..d+3, same n) with
// float4 loads. Chunk summaries (E, g, WE per rec; AL per thread) recombined
// exactly in LDS.
__global__ __launch_bounds__(1024, 2) void k3_scan(float* __restrict__ ws) {
    __shared__ float E_s[4096], g_s[4096], WE_s[4096], AL_s[1024];
    __shared__ float red_s[256];
    const float* dt_g  = ws + WS_DT;
    const float* dtu_g = dt_g + STRIDE_BD;
    const float* sv_g  = dt_g + 2 * STRIDE_BD;
    const float* bc_g  = dt_g + 3 * STRIDE_BD;

    int t = threadIdx.x;
    int c = t >> 6;                  // L-chunk 0..15
    int l6 = t & 63;
    int bk = blockIdx.x;
    int b = bk >> 4;
    int dgroup = (bk >> 2) & 3;
    int ngroup = bk & 3;
    int d = dgroup * 64 + (l6 & 15) * 4;
    int n = ngroup * 4 + (l6 >> 4);
    int l0 = c << 6;                 // chunk base in L (64 per chunk)

    float a0 = ws[WS_ANEG + (d + 0) * 16 + n];
    float a1 = ws[WS_ANEG + (d + 1) * 16 + n];
    float a2 = ws[WS_ANEG + (d + 2) * 16 + n];
    float a3 = ws[WS_ANEG + (d + 3) * 16 + n];

    size_t base = (size_t)b * 262144 + (size_t)l0 * 256 + d;
    const float4* dt4  = (const float4*)(dt_g  + base);
    const float4* dtu4 = (const float4*)(dtu_g + base);
    const float4* sv4  = (const float4*)(sv_g  + base);
    const float* bcp = bc_g + (size_t)b * 32768 + (size_t)l0 * 32 + n;

    float E0 = 1.f, E1 = 1.f, E2 = 1.f, E3 = 1.f;
    float g0 = 0.f, g1 = 0.f, g2 = 0.f, g3 = 0.f;
    float W0 = 0.f, W1 = 0.f, W2 = 0.f, W3 = 0.f;
    float accL = 0.f;
    #pragma unroll 2
    for (int l = 0; l < 64; ++l) {
        float4 dt = dt4[l * 64];
        float4 du = dtu4[l * 64];
        float4 sv = sv4[l * 64];
        float Bv = bcp[l * 32];
        float Cv = bcp[l * 32 + 16];
        #define K3_STEP(J, C4) { \
            float dA = __expf(dt.C4 * a##J); \
            g##J = fmaf(dA, g##J, du.C4 * Bv); \
            E##J *= dA; \
            float wt = Cv * sv.C4; \
            accL = fmaf(g##J, wt, accL); \
            W##J = fmaf(E##J, wt, W##J); }
        K3_STEP(0, x)
        K3_STEP(1, y)
        K3_STEP(2, z)
        K3_STEP(3, w)
        #undef K3_STEP
    }
    // SoA by rec-slot j: E_s[j*1024 + t] (stride-1 writes, conflict-free)
    E_s[t] = E0; E_s[1024 + t] = E1; E_s[2048 + t] = E2; E_s[3072 + t] = E3;
    g_s[t] = g0; g_s[1024 + t] = g1; g_s[2048 + t] = g2; g_s[3072 + t] = g3;
    WE_s[t] = W0; WE_s[1024 + t] = W1; WE_s[2048 + t] = W2; WE_s[3072 + t] = W3;
    AL_s[t] = accL;
    __syncthreads();

    // Phase B: 256 threads, each chains one (rec l6, slot j) across 16 chunks.
    if (t < 256) {
        int rl6 = t >> 2;
        int j = t & 3;
        int idx = j * 1024 + rl6;
        float h = 0.f, hw = 0.f;
        #pragma unroll
        for (int cc = 0; cc < 16; ++cc) {
            int o = idx + cc * 64;
            hw = fmaf(h, WE_s[o], hw);
            h = fmaf(E_s[o], h, g_s[o]);
        }
        red_s[t] = hw + AL_s[t] + AL_s[256 + t] + AL_s[512 + t] + AL_s[768 + t];
    }
    __syncthreads();
    for (int st = 128; st > 0; st >>= 1) {
        if (t < st) red_s[t] += red_s[t + st];
        __syncthreads();
    }
    if (t == 0) ws[WS_S2 + blockIdx.x] = red_s[0];
}

__global__ void k4_final(const float* __restrict__ b_fc, const float* __restrict__ ws,
                         float* __restrict__ out) {
    int b = threadIdx.x;
    if (b < 32) {
        float s = 0.f;
        for (int k = 0; k < 32; ++k) s += ws[WS_S1 + b * 32 + k];
        for (int k = 0; k < 16; ++k) s += ws[WS_S2 + b * 16 + k];
        float logit = s * (1.f / 1024.f) + b_fc[0];
        out[b] = __fdividef(1.f, 1.f + __expf(-logit));
    }
}

extern "C" void kernel_launch(void* const* d_in, const int* in_sizes, int n_in,
                              void* d_out, int out_size, void* d_ws, size_t ws_size,
                              hipStream_t stream) {
    const float* x      = (const float*)d_in[0];
    const float* W_emb  = (const float*)d_in[1];
    const float* b_emb  = (const float*)d_in[2];
    const float* W_in   = (const float*)d_in[3];
    const float* conv_w = (const float*)d_in[4];
    const float* conv_b = (const float*)d_in[5];
    const float* W_x    = (const float*)d_in[6];
    const float* W_dt   = (const float*)d_in[7];
    const float* b_dt   = (const float*)d_in[8];
    const float* A_log  = (const float*)d_in[9];
    const float* Dvec   = (const float*)d_in[10];
    const float* W_out  = (const float*)d_in[11];
    const float* W_fc   = (const float*)d_in[12];
    const float* b_fc   = (const float*)d_in[13];
    float* ws = (float*)d_ws;

    k0_precompute<<<67, 256, 0, stream>>>(W_emb, b_emb, W_in, W_x, A_log, W_out, W_fc, ws);
    k1_front<<<1024, 256, 0, stream>>>(x, conv_w, conv_b, W_dt, b_dt, Dvec, ws);
    k3_scan<<<512, 1024, 0, stream>>>(ws);
    k4_final<<<1, 64, 0, stream>>>(b_fc, ws, (float*)d_out);
}

// Round 5
// 209.988 us; speedup vs baseline: 1.2636x; 1.0204x over previous
//
#include <hip/hip_runtime.h>

// Problem constants: B=32, L=1024, D_MODEL=128, D_INNER=256, D_STATE=16, D_CONV=4, DT_RANK=8
// Workspace layout (float offsets):
#define WS_P    0        // p[512]   = W_in @ W_emb[:,0]
#define WS_Q    512      // q[512]   = W_in @ b_emb
#define WS_V    1024     // v[256]   = W_out^T @ W_fc^T
#define WS_ANEG 1280     // aneg[256*16] = -exp(A_log)
#define WS_WXT  5376     // WxT[256][48] padded
#define WS_S1   17664    // slot1[1024]  per-k1-block partial of sum(u*D*silu(z)*v)
#define WS_S2   18688    // slot2[256]   per-k3-block partial (bk = dg*32 + b)
#define WS_DT   19200    // dt  [32768*256]
#define STRIDE_BD 8388608
// dtu = WS_DT + STRIDE_BD, sv = +2*STRIDE_BD, bc = +3*STRIDE_BD (32768*32)

__global__ void k0_precompute(const float* __restrict__ W_emb,
                              const float* __restrict__ b_emb,
                              const float* __restrict__ W_in,
                              const float* __restrict__ W_x,
                              const float* __restrict__ A_log,
                              const float* __restrict__ W_out,
                              const float* __restrict__ W_fc,
                              float* __restrict__ ws) {
    int idx = blockIdx.x * 256 + threadIdx.x;
    if (idx < 512) {
        float sp = 0.f, sq = 0.f;
        const float* row = W_in + idx * 128;
        for (int d = 0; d < 128; ++d) {
            float w = row[d];
            sp = fmaf(w, W_emb[d], sp);
            sq = fmaf(w, b_emb[d], sq);
        }
        ws[WS_P + idx] = sp;
        ws[WS_Q + idx] = sq;
    } else if (idx < 768) {
        int d = idx - 512;
        float s = 0.f;
        for (int e = 0; e < 128; ++e) s = fmaf(W_fc[e], W_out[e * 256 + d], s);
        ws[WS_V + d] = s;
    } else if (idx < 4864) {
        int i = idx - 768;
        ws[WS_ANEG + i] = -__expf(A_log[i]);
    } else if (idx < 17152) {
        int i = idx - 4864;            // [0, 256*48)
        int d = i / 48, c = i - d * 48;
        int g = c / 12, cj = c - g * 12;
        ws[WS_WXT + i] = (cj < 10) ? W_x[(g * 10 + cj) * 256 + d] : 0.f;
    }
}

// Fused front-end: per block = 32 consecutive positions of one batch row.
__global__ __launch_bounds__(256, 4) void k1_front(
        const float* __restrict__ x,
        const float* __restrict__ conv_w,
        const float* __restrict__ conv_b,
        const float* __restrict__ W_dt,
        const float* __restrict__ b_dt,
        const float* __restrict__ Dvec,
        float* __restrict__ ws) {
    __shared__ float u_s[32 * 257];   // [pos][d]
    __shared__ float xdb_s[32 * 41];  // [pos][j]
    __shared__ float x_s[36];
    __shared__ float red_s[256];

    const float* p = ws + WS_P;
    const float* q = ws + WS_Q;
    const float* v = ws + WS_V;
    const float* wxt = ws + WS_WXT;
    float* dt_g  = ws + WS_DT;
    float* dtu_g = dt_g + STRIDE_BD;
    float* sv_g  = dt_g + 2 * STRIDE_BD;
    float* bc_g  = dt_g + 3 * STRIDE_BD;

    int t = threadIdx.x;
    int b = blockIdx.x >> 5;
    int l0 = (blockIdx.x & 31) << 5;
    long posbase = b * 1024 + l0;

    if (t < 35) {
        int gi = l0 - 3 + t;
        x_s[t] = (gi >= 0) ? x[b * 1024 + gi] : 0.f;
    }

    float pd = p[t], qd = q[t], pz = p[256 + t], qz = q[256 + t];
    float cw0 = conv_w[t], cw1 = conv_w[256 + t], cw2 = conv_w[512 + t], cw3 = conv_w[768 + t];
    float cb = conv_b[t], Dd = Dvec[t], vd = v[t];
    float wdt[8];
    #pragma unroll
    for (int r = 0; r < 8; ++r) wdt[r] = W_dt[t * 8 + r];
    float bdt = b_dt[t];
    __syncthreads();

    // Stage 1: conv -> u = silu(xc); z-gate -> sv = silu(z)*v[d]
    float uDsv = 0.f;
    for (int pp = 0; pp < 32; ++pp) {
        int l = l0 + pp;
        float x0 = x_s[pp + 3];
        float s = cb + cw3 * fmaf(x0, pd, qd);
        if (l >= 3) {
            s += cw0 * fmaf(x_s[pp], pd, qd)
               + cw1 * fmaf(x_s[pp + 1], pd, qd)
               + cw2 * fmaf(x_s[pp + 2], pd, qd);
        } else {
            if (l >= 1) s += cw2 * fmaf(x_s[pp + 2], pd, qd);
            if (l >= 2) s += cw1 * fmaf(x_s[pp + 1], pd, qd);
        }
        float u = __fdividef(s, 1.f + __expf(-s));
        float z = fmaf(x0, pz, qz);
        float svv = __fdividef(z, 1.f + __expf(-z)) * vd;
        u_s[pp * 257 + t] = u;
        sv_g[(size_t)(posbase + pp) * 256 + t] = svv;
        uDsv = fmaf(u * Dd, svv, uDsv);
    }
    __syncthreads();

    // Stage 2: x_db GEMV with pos-register-blocking
    {
        int w = t >> 6;
        int lane = t & 63;
        int pg = lane >> 3;
        int ds = lane & 7;
        float acc[4][10];
        #pragma unroll
        for (int pp = 0; pp < 4; ++pp)
            #pragma unroll
            for (int jj = 0; jj < 10; ++jj) acc[pp][jj] = 0.f;
        const float* wbase = wxt + w * 12;
        const float* ub = u_s + (pg * 4) * 257;
        for (int i = 0; i < 32; ++i) {
            int dd = ds + 8 * i;
            const float* wr = wbase + dd * 48;
            float4 w0 = *(const float4*)wr;
            float4 w1 = *(const float4*)(wr + 4);
            float2 w2 = *(const float2*)(wr + 8);
            float u0 = ub[dd];
            float u1 = ub[257 + dd];
            float u2 = ub[2 * 257 + dd];
            float u3 = ub[3 * 257 + dd];
            #define K1_FMAS(pp, uv) \
                acc[pp][0] = fmaf(uv, w0.x, acc[pp][0]); \
                acc[pp][1] = fmaf(uv, w0.y, acc[pp][1]); \
                acc[pp][2] = fmaf(uv, w0.z, acc[pp][2]); \
                acc[pp][3] = fmaf(uv, w0.w, acc[pp][3]); \
                acc[pp][4] = fmaf(uv, w1.x, acc[pp][4]); \
                acc[pp][5] = fmaf(uv, w1.y, acc[pp][5]); \
                acc[pp][6] = fmaf(uv, w1.z, acc[pp][6]); \
                acc[pp][7] = fmaf(uv, w1.w, acc[pp][7]); \
                acc[pp][8] = fmaf(uv, w2.x, acc[pp][8]); \
                acc[pp][9] = fmaf(uv, w2.y, acc[pp][9]);
            K1_FMAS(0, u0)
            K1_FMAS(1, u1)
            K1_FMAS(2, u2)
            K1_FMAS(3, u3)
            #undef K1_FMAS
        }
        #pragma unroll
        for (int m = 1; m <= 4; m <<= 1)
            #pragma unroll
            for (int pp = 0; pp < 4; ++pp)
                #pragma unroll
                for (int jj = 0; jj < 10; ++jj)
                    acc[pp][jj] += __shfl_xor(acc[pp][jj], m);
        if (ds == 0) {
            #pragma unroll
            for (int pp = 0; pp < 4; ++pp)
                #pragma unroll
                for (int jj = 0; jj < 10; ++jj)
                    xdb_s[(pg * 4 + pp) * 41 + w * 10 + jj] = acc[pp][jj];
        }
    }
    __syncthreads();

    // Stage 3: dt = softplus(...); store dt, dtu coalesced
    for (int pp = 0; pp < 32; ++pp) {
        const float* xr = xdb_s + pp * 41;
        float s = bdt;
        #pragma unroll
        for (int r = 0; r < 8; ++r) s = fmaf(xr[r], wdt[r], s);
        float dtv = fmaxf(s, 0.f) + log1pf(__expf(-fabsf(s)));
        float uv = u_s[pp * 257 + t];
        size_t off = (size_t)(posbase + pp) * 256 + t;
        dt_g[off] = dtv;
        dtu_g[off] = dtv * uv;
    }

    // Stage 4: write Bs|Cs as [pos][32]
    {
        int pp = t >> 3;
        int j0 = (t & 7) * 4;
        size_t off = (size_t)(posbase + pp) * 32 + j0;
        #pragma unroll
        for (int j = 0; j < 4; ++j) bc_g[off + j] = xdb_s[pp * 41 + 8 + j0 + j];
    }

    // Stage 5: block partial for the u*D*sv term
    red_s[t] = uDsv;
    __syncthreads();
    for (int st = 128; st > 0; st >>= 1) {
        if (t < st) red_s[t] += red_s[t + st];
        __syncthreads();
    }
    if (t == 0) ws[WS_S1 + blockIdx.x] = red_s[0];
}

// Scan: 256 blocks = (dg:8)*(b:32), bk = dg*32 + b (same-b blocks share an XCD
// for bc L2 reuse). Block covers 32 d x 16 n x L=1024; each (l,d) element
// fetched exactly once per chip. 1024 threads = 8 L-chunks x 8 d-quads x 16 n;
// 16 n-lanes issue identical dt/dtu/sv addresses (coalesced broadcast).
// Chunk summaries recombined exactly in LDS.
__global__ __launch_bounds__(1024, 4) void k3_scan(float* __restrict__ ws) {
    __shared__ float E_s[4096], g_s[4096], WE_s[4096], AL_s[1024];
    __shared__ float red_s[512];
    const float* dt_g  = ws + WS_DT;
    const float* dtu_g = dt_g + STRIDE_BD;
    const float* sv_g  = dt_g + 2 * STRIDE_BD;
    const float* bc_g  = dt_g + 3 * STRIDE_BD;

    int t = threadIdx.x;
    int c = t >> 7;                  // L-chunk 0..7 (128 steps each)
    int r7 = t & 127;
    int qd = r7 >> 4;                // d-quad 0..7
    int n = r7 & 15;
    int bk = blockIdx.x;
    int b = bk & 31;
    int dg = bk >> 5;
    int d = dg * 32 + qd * 4;
    int l0 = c << 7;

    float a0 = ws[WS_ANEG + (d + 0) * 16 + n];
    float a1 = ws[WS_ANEG + (d + 1) * 16 + n];
    float a2 = ws[WS_ANEG + (d + 2) * 16 + n];
    float a3 = ws[WS_ANEG + (d + 3) * 16 + n];

    size_t base = (size_t)b * 262144 + (size_t)l0 * 256 + d;
    const float4* dt4  = (const float4*)(dt_g  + base);
    const float4* dtu4 = (const float4*)(dtu_g + base);
    const float4* sv4  = (const float4*)(sv_g  + base);
    const float* bcp = bc_g + (size_t)b * 32768 + (size_t)l0 * 32 + n;

    float E0 = 1.f, E1 = 1.f, E2 = 1.f, E3 = 1.f;
    float g0 = 0.f, g1 = 0.f, g2 = 0.f, g3 = 0.f;
    float W0 = 0.f, W1 = 0.f, W2 = 0.f, W3 = 0.f;
    float accL = 0.f;
    #pragma unroll 4
    for (int l = 0; l < 128; ++l) {
        float4 dt = dt4[l * 64];
        float4 du = dtu4[l * 64];
        float4 sv = sv4[l * 64];
        float Bv = bcp[l * 32];
        float Cv = bcp[l * 32 + 16];
        #define K3_STEP(J, C4) { \
            float dA = __expf(dt.C4 * a##J); \
            g##J = fmaf(dA, g##J, du.C4 * Bv); \
            E##J *= dA; \
            float wt = Cv * sv.C4; \
            accL = fmaf(g##J, wt, accL); \
            W##J = fmaf(E##J, wt, W##J); }
        K3_STEP(0, x)
        K3_STEP(1, y)
        K3_STEP(2, z)
        K3_STEP(3, w)
        #undef K3_STEP
    }
    // SoA by rec-slot j (d within quad): E_s[j*1024 + t], stride-1 writes
    E_s[t] = E0; E_s[1024 + t] = E1; E_s[2048 + t] = E2; E_s[3072 + t] = E3;
    g_s[t] = g0; g_s[1024 + t] = g1; g_s[2048 + t] = g2; g_s[3072 + t] = g3;
    WE_s[t] = W0; WE_s[1024 + t] = W1; WE_s[2048 + t] = W2; WE_s[3072 + t] = W3;
    AL_s[t] = accL;
    __syncthreads();

    // Phase B: 512 threads, each chains one rec (j, qd, n) across 8 chunks.
    // Reads stride-1 across threads (conflict-free).
    if (t < 512) {
        int j = t >> 7;
        int rqn = t & 127;           // qd*16 + n
        int idx = j * 1024 + rqn;
        float h = 0.f, hw = 0.f;
        #pragma unroll
        for (int cc = 0; cc < 8; ++cc) {
            int o = idx + cc * 128;
            hw = fmaf(h, WE_s[o], hw);
            h = fmaf(E_s[o], h, g_s[o]);
        }
        red_s[t] = hw + AL_s[t] + AL_s[512 + t];
    }
    __syncthreads();
    for (int st = 256; st > 0; st >>= 1) {
        if (t < st) red_s[t] += red_s[t + st];
        __syncthreads();
    }
    if (t == 0) ws[WS_S2 + bk] = red_s[0];
}

__global__ void k4_final(const float* __restrict__ b_fc, const float* __restrict__ ws,
                         float* __restrict__ out) {
    int b = threadIdx.x;
    if (b < 32) {
        float s = 0.f;
        for (int k = 0; k < 32; ++k) s += ws[WS_S1 + b * 32 + k];
        for (int k = 0; k < 8; ++k) s += ws[WS_S2 + k * 32 + b];
        float logit = s * (1.f / 1024.f) + b_fc[0];
        out[b] = __fdividef(1.f, 1.f + __expf(-logit));
    }
}

extern "C" void kernel_launch(void* const* d_in, const int* in_sizes, int n_in,
                              void* d_out, int out_size, void* d_ws, size_t ws_size,
                              hipStream_t stream) {
    const float* x      = (const float*)d_in[0];
    const float* W_emb  = (const float*)d_in[1];
    const float* b_emb  = (const float*)d_in[2];
    const float* W_in   = (const float*)d_in[3];
    const float* conv_w = (const float*)d_in[4];
    const float* conv_b = (const float*)d_in[5];
    const float* W_x    = (const float*)d_in[6];
    const float* W_dt   = (const float*)d_in[7];
    const float* b_dt   = (const float*)d_in[8];
    const float* A_log  = (const float*)d_in[9];
    const float* Dvec   = (const float*)d_in[10];
    const float* W_out  = (const float*)d_in[11];
    const float* W_fc   = (const float*)d_in[12];
    const float* b_fc   = (const float*)d_in[13];
    float* ws = (float*)d_ws;

    k0_precompute<<<67, 256, 0, stream>>>(W_emb, b_emb, W_in, W_x, A_log, W_out, W_fc, ws);
    k1_front<<<1024, 256, 0, stream>>>(x, conv_w, conv_b, W_dt, b_dt, Dvec, ws);
    k3_scan<<<256, 1024, 0, stream>>>(ws);
    k4_final<<<1, 64, 0, stream>>>(b_fc, ws, (float*)d_out);
}

// Round 6
// 201.478 us; speedup vs baseline: 1.3169x; 1.0422x over previous
//
#include <hip/hip_runtime.h>

// Problem constants: B=32, L=1024, D_MODEL=128, D_INNER=256, D_STATE=16, D_CONV=4, DT_RANK=8
// Workspace layout (float offsets):
#define WS_P    0        // p[512]   = W_in @ W_emb[:,0]
#define WS_Q    512      // q[512]   = W_in @ b_emb
#define WS_V    1024     // v[256]   = W_out^T @ W_fc^T
#define WS_ANEG 1280     // aneg[256*16] = -exp(A_log)
#define WS_WXT  5376     // WxT[256][48] padded
#define WS_S1   17664    // slot1[1024]  per-k1-block partial of sum(u*D*silu(z)*v)
#define WS_S2   18688    // slot2[256]   per-k3-block partial (bk = dg*32 + b)
#define WS_PACK 19200    // pack[dg:8][b:32][l:1024][q:8][12] = {dt x4, dtu x4, sv x4}
#define WS_BC   25185024 // bc[b:32][l:1024][32] = Bs|Cs
// total 26233600 floats ~= 105 MB

__global__ void k0_precompute(const float* __restrict__ W_emb,
                              const float* __restrict__ b_emb,
                              const float* __restrict__ W_in,
                              const float* __restrict__ W_x,
                              const float* __restrict__ A_log,
                              const float* __restrict__ W_out,
                              const float* __restrict__ W_fc,
                              float* __restrict__ ws) {
    int idx = blockIdx.x * 256 + threadIdx.x;
    if (idx < 512) {
        float sp = 0.f, sq = 0.f;
        const float* row = W_in + idx * 128;
        for (int d = 0; d < 128; ++d) {
            float w = row[d];
            sp = fmaf(w, W_emb[d], sp);
            sq = fmaf(w, b_emb[d], sq);
        }
        ws[WS_P + idx] = sp;
        ws[WS_Q + idx] = sq;
    } else if (idx < 768) {
        int d = idx - 512;
        float s = 0.f;
        for (int e = 0; e < 128; ++e) s = fmaf(W_fc[e], W_out[e * 256 + d], s);
        ws[WS_V + d] = s;
    } else if (idx < 4864) {
        int i = idx - 768;
        ws[WS_ANEG + i] = -__expf(A_log[i]);
    } else if (idx < 17152) {
        int i = idx - 4864;            // [0, 256*48)
        int d = i / 48, c = i - d * 48;
        int g = c / 12, cj = c - g * 12;
        ws[WS_WXT + i] = (cj < 10) ? W_x[(g * 10 + cj) * 256 + d] : 0.f;
    }
}

// Fused front-end: per block = 32 consecutive positions of one batch row.
__global__ __launch_bounds__(256, 4) void k1_front(
        const float* __restrict__ x,
        const float* __restrict__ conv_w,
        const float* __restrict__ conv_b,
        const float* __restrict__ W_dt,
        const float* __restrict__ b_dt,
        const float* __restrict__ Dvec,
        float* __restrict__ ws) {
    __shared__ float u_s[32 * 257];   // [pos][d]
    __shared__ float xdb_s[32 * 41];  // [pos][j]
    __shared__ float x_s[36];
    __shared__ float red_s[256];

    const float* p = ws + WS_P;
    const float* q = ws + WS_Q;
    const float* v = ws + WS_V;
    const float* wxt = ws + WS_WXT;
    float* pack_g = ws + WS_PACK;
    float* bc_g   = ws + WS_BC;

    int t = threadIdx.x;
    int b = blockIdx.x >> 5;
    int l0 = (blockIdx.x & 31) << 5;
    long posbase = b * 1024 + l0;

    // pack addressing for channel t = d
    int dgc = t >> 5;                 // d-group 0..7
    int qc  = (t >> 2) & 7;           // quad within group
    int jc  = t & 3;                  // slot within quad
    int slotbase = qc * 12 + jc;
    size_t packrow = (size_t)dgc * 32768 + (size_t)posbase;  // row index into [.,96]

    if (t < 35) {
        int gi = l0 - 3 + t;
        x_s[t] = (gi >= 0) ? x[b * 1024 + gi] : 0.f;
    }

    float pd = p[t], qd = q[t], pz = p[256 + t], qz = q[256 + t];
    float cw0 = conv_w[t], cw1 = conv_w[256 + t], cw2 = conv_w[512 + t], cw3 = conv_w[768 + t];
    float cb = conv_b[t], Dd = Dvec[t], vd = v[t];
    float wdt[8];
    #pragma unroll
    for (int r = 0; r < 8; ++r) wdt[r] = W_dt[t * 8 + r];
    float bdt = b_dt[t];
    __syncthreads();

    // Stage 1: conv -> u = silu(xc); z-gate -> sv = silu(z)*v[d]
    float uDsv = 0.f;
    for (int pp = 0; pp < 32; ++pp) {
        int l = l0 + pp;
        float x0 = x_s[pp + 3];
        float s = cb + cw3 * fmaf(x0, pd, qd);
        if (l >= 3) {
            s += cw0 * fmaf(x_s[pp], pd, qd)
               + cw1 * fmaf(x_s[pp + 1], pd, qd)
               + cw2 * fmaf(x_s[pp + 2], pd, qd);
        } else {
            if (l >= 1) s += cw2 * fmaf(x_s[pp + 2], pd, qd);
            if (l >= 2) s += cw1 * fmaf(x_s[pp + 1], pd, qd);
        }
        float u = __fdividef(s, 1.f + __expf(-s));
        float z = fmaf(x0, pz, qz);
        float svv = __fdividef(z, 1.f + __expf(-z)) * vd;
        u_s[pp * 257 + t] = u;
        pack_g[(packrow + pp) * 96 + slotbase + 8] = svv;
        uDsv = fmaf(u * Dd, svv, uDsv);
    }
    __syncthreads();

    // Stage 2: x_db GEMV with pos-register-blocking
    {
        int w = t >> 6;
        int lane = t & 63;
        int pg = lane >> 3;
        int ds = lane & 7;
        float acc[4][10];
        #pragma unroll
        for (int pp = 0; pp < 4; ++pp)
            #pragma unroll
            for (int jj = 0; jj < 10; ++jj) acc[pp][jj] = 0.f;
        const float* wbase = wxt + w * 12;
        const float* ub = u_s + (pg * 4) * 257;
        for (int i = 0; i < 32; ++i) {
            int dd = ds + 8 * i;
            const float* wr = wbase + dd * 48;
            float4 w0 = *(const float4*)wr;
            float4 w1 = *(const float4*)(wr + 4);
            float2 w2 = *(const float2*)(wr + 8);
            float u0 = ub[dd];
            float u1 = ub[257 + dd];
            float u2 = ub[2 * 257 + dd];
            float u3 = ub[3 * 257 + dd];
            #define K1_FMAS(pp, uv) \
                acc[pp][0] = fmaf(uv, w0.x, acc[pp][0]); \
                acc[pp][1] = fmaf(uv, w0.y, acc[pp][1]); \
                acc[pp][2] = fmaf(uv, w0.z, acc[pp][2]); \
                acc[pp][3] = fmaf(uv, w0.w, acc[pp][3]); \
                acc[pp][4] = fmaf(uv, w1.x, acc[pp][4]); \
                acc[pp][5] = fmaf(uv, w1.y, acc[pp][5]); \
                acc[pp][6] = fmaf(uv, w1.z, acc[pp][6]); \
                acc[pp][7] = fmaf(uv, w1.w, acc[pp][7]); \
                acc[pp][8] = fmaf(uv, w2.x, acc[pp][8]); \
                acc[pp][9] = fmaf(uv, w2.y, acc[pp][9]);
            K1_FMAS(0, u0)
            K1_FMAS(1, u1)
            K1_FMAS(2, u2)
            K1_FMAS(3, u3)
            #undef K1_FMAS
        }
        #pragma unroll
        for (int m = 1; m <= 4; m <<= 1)
            #pragma unroll
            for (int pp = 0; pp < 4; ++pp)
                #pragma unroll
                for (int jj = 0; jj < 10; ++jj)
                    acc[pp][jj] += __shfl_xor(acc[pp][jj], m);
        if (ds == 0) {
            #pragma unroll
            for (int pp = 0; pp < 4; ++pp)
                #pragma unroll
                for (int jj = 0; jj < 10; ++jj)
                    xdb_s[(pg * 4 + pp) * 41 + w * 10 + jj] = acc[pp][jj];
        }
    }
    __syncthreads();

    // Stage 3: dt = softplus(...); store dt, dtu into pack
    for (int pp = 0; pp < 32; ++pp) {
        const float* xr = xdb_s + pp * 41;
        float s = bdt;
        #pragma unroll
        for (int r = 0; r < 8; ++r) s = fmaf(xr[r], wdt[r], s);
        float dtv = fmaxf(s, 0.f) + log1pf(__expf(-fabsf(s)));
        float uv = u_s[pp * 257 + t];
        size_t off = (packrow + pp) * 96 + slotbase;
        pack_g[off] = dtv;
        pack_g[off + 4] = dtv * uv;
    }

    // Stage 4: write Bs|Cs as [pos][32]
    {
        int pp = t >> 3;
        int j0 = (t & 7) * 4;
        size_t off = (size_t)(posbase + pp) * 32 + j0;
        #pragma unroll
        for (int j = 0; j < 4; ++j) bc_g[off + j] = xdb_s[pp * 41 + 8 + j0 + j];
    }

    // Stage 5: block partial for the u*D*sv term
    red_s[t] = uDsv;
    __syncthreads();
    for (int st = 128; st > 0; st >>= 1) {
        if (t < st) red_s[t] += red_s[t + st];
        __syncthreads();
    }
    if (t == 0) ws[WS_S1 + blockIdx.x] = red_s[0];
}

// Scan: 256 blocks = (dg:8)*(b:32), bk = dg*32 + b. Block covers 32 d x 16 n x
// L=1024 and reads ONE contiguous 4.7 MB pack stream (384 B per l-step) plus a
// sequential bc stream. 1024 threads = 8 L-chunks x 8 d-quads x 16 n; 16
// n-lanes broadcast-share each pack load. Exact LDS recombination.
__global__ __launch_bounds__(1024, 4) void k3_scan(float* __restrict__ ws) {
    __shared__ float E_s[4096], g_s[4096], WE_s[4096], AL_s[1024];
    __shared__ float red_s[512];
    const float* pack_g = ws + WS_PACK;
    const float* bc_g   = ws + WS_BC;

    int t = threadIdx.x;
    int c = t >> 7;                  // L-chunk 0..7 (128 steps each)
    int r7 = t & 127;
    int qd = r7 >> 4;                // d-quad 0..7
    int n = r7 & 15;
    int bk = blockIdx.x;
    int b = bk & 31;
    int dg = bk >> 5;
    int d = dg * 32 + qd * 4;
    int l0 = c << 7;

    float a0 = ws[WS_ANEG + (d + 0) * 16 + n];
    float a1 = ws[WS_ANEG + (d + 1) * 16 + n];
    float a2 = ws[WS_ANEG + (d + 2) * 16 + n];
    float a3 = ws[WS_ANEG + (d + 3) * 16 + n];

    const float* pk = pack_g + ((size_t)dg * 32768 + (size_t)b * 1024 + l0) * 96 + qd * 12;
    const float* bcp = bc_g + (size_t)b * 32768 + (size_t)l0 * 32 + n;

    float E0 = 1.f, E1 = 1.f, E2 = 1.f, E3 = 1.f;
    float g0 = 0.f, g1 = 0.f, g2 = 0.f, g3 = 0.f;
    float W0 = 0.f, W1 = 0.f, W2 = 0.f, W3 = 0.f;
    float accL = 0.f;
    #pragma unroll 8
    for (int l = 0; l < 128; ++l) {
        float4 dt = *(const float4*)(pk + (size_t)l * 96);
        float4 du = *(const float4*)(pk + (size_t)l * 96 + 4);
        float4 sv = *(const float4*)(pk + (size_t)l * 96 + 8);
        float Bv = bcp[l * 32];
        float Cv = bcp[l * 32 + 16];
        #define K3_STEP(J, C4) { \
            float dA = __expf(dt.C4 * a##J); \
            g##J = fmaf(dA, g##J, du.C4 * Bv); \
            E##J *= dA; \
            float wt = Cv * sv.C4; \
            accL = fmaf(g##J, wt, accL); \
            W##J = fmaf(E##J, wt, W##J); }
        K3_STEP(0, x)
        K3_STEP(1, y)
        K3_STEP(2, z)
        K3_STEP(3, w)
        #undef K3_STEP
    }
    // SoA by rec-slot j (d within quad): E_s[j*1024 + t], stride-1 writes
    E_s[t] = E0; E_s[1024 + t] = E1; E_s[2048 + t] = E2; E_s[3072 + t] = E3;
    g_s[t] = g0; g_s[1024 + t] = g1; g_s[2048 + t] = g2; g_s[3072 + t] = g3;
    WE_s[t] = W0; WE_s[1024 + t] = W1; WE_s[2048 + t] = W2; WE_s[3072 + t] = W3;
    AL_s[t] = accL;
    __syncthreads();

    // Phase B: 512 threads, each chains one rec (j, qd, n) across 8 chunks.
    if (t < 512) {
        int j = t >> 7;
        int rqn = t & 127;           // qd*16 + n
        int idx = j * 1024 + rqn;
        float h = 0.f, hw = 0.f;
        #pragma unroll
        for (int cc = 0; cc < 8; ++cc) {
            int o = idx + cc * 128;
            hw = fmaf(h, WE_s[o], hw);
            h = fmaf(E_s[o], h, g_s[o]);
        }
        red_s[t] = hw + AL_s[t] + AL_s[512 + t];
    }
    __syncthreads();
    for (int st = 256; st > 0; st >>= 1) {
        if (t < st) red_s[t] += red_s[t + st];
        __syncthreads();
    }
    if (t == 0) ws[WS_S2 + bk] = red_s[0];
}

__global__ void k4_final(const float* __restrict__ b_fc, const float* __restrict__ ws,
                         float* __restrict__ out) {
    int b = threadIdx.x;
    if (b < 32) {
        float s = 0.f;
        for (int k = 0; k < 32; ++k) s += ws[WS_S1 + b * 32 + k];
        for (int k = 0; k < 8; ++k) s += ws[WS_S2 + k * 32 + b];
        float logit = s * (1.f / 1024.f) + b_fc[0];
        out[b] = __fdividef(1.f, 1.f + __expf(-logit));
    }
}

extern "C" void kernel_launch(void* const* d_in, const int* in_sizes, int n_in,
                              void* d_out, int out_size, void* d_ws, size_t ws_size,
                              hipStream_t stream) {
    const float* x      = (const float*)d_in[0];
    const float* W_emb  = (const float*)d_in[1];
    const float* b_emb  = (const float*)d_in[2];
    const float* W_in   = (const float*)d_in[3];
    const float* conv_w = (const float*)d_in[4];
    const float* conv_b = (const float*)d_in[5];
    const float* W_x    = (const float*)d_in[6];
    const float* W_dt   = (const float*)d_in[7];
    const float* b_dt   = (const float*)d_in[8];
    const float* A_log  = (const float*)d_in[9];
    const float* Dvec   = (const float*)d_in[10];
    const float* W_out  = (const float*)d_in[11];
    const float* W_fc   = (const float*)d_in[12];
    const float* b_fc   = (const float*)d_in[13];
    float* ws = (float*)d_ws;

    k0_precompute<<<67, 256, 0, stream>>>(W_emb, b_emb, W_in, W_x, A_log, W_out, W_fc, ws);
    k1_front<<<1024, 256, 0, stream>>>(x, conv_w, conv_b, W_dt, b_dt, Dvec, ws);
    k3_scan<<<256, 1024, 0, stream>>>(ws);
    k4_final<<<1, 64, 0, stream>>>(b_fc, ws, (float*)d_out);
}